// Round 18
// baseline (206.829 us; speedup 1.0000x reference)
//
#include <hip/hip_runtime.h>
#include <hip/hip_bf16.h>
#include <hip/hip_fp8.h>

#define N_ROWS 4096
#define TWO_N 8192
#define DIM 512                             // elements per row; fp8 row = 512 B
#define BKB 64                              // K bytes per iter in fp8
#define NKS (DIM / BKB)                     // 8 K-steps
#define QCAP 260                            // tiles per vxcd queue (8*260=2080)
#define INV_T 14.285714285714286f           // 1/0.07
#define LOG2E 1.4426950408889634f
#define C_LOG2E 20.60992915555662f          // (1/0.07)*log2(e)
#define INV_SQRT_T 3.7796447300922722f      // 1/sqrt(0.07)

typedef float f32x4 __attribute__((ext_vector_type(4)));
typedef long fp8x8;                          // 8 fp8 = one 64-bit MFMA operand
typedef long fp8x8x2 __attribute__((ext_vector_type(2)));   // b128 = 2 operands

#define ASYNC_COPY16(gp, lp)                                                     \
  __builtin_amdgcn_global_load_lds((const __attribute__((address_space(1))) void*)(gp), \
                                   (__attribute__((address_space(3))) void*)(lp), 16, 0, 0)

#define VMCNT(n) asm volatile("s_waitcnt vmcnt(" #n ")" ::: "memory")

// Wave-per-row prep: float4 loads, butterfly shuffle reduce, fp8 e4m3 pack.
// Zn is stored K-PERMUTED: within each 64B k-block, 8B slot l (k=l*8..l*8+7)
// is placed at position (l&3)*16 + (l>>2)*8 (order [0,4,1,5,2,6,3,7]) so the
// two operands MFMA-lane q needs (slots q, q+4) are ADJACENT -> one b128
// read per fragment pair in k_lse. Exact: a global k-permutation of the
// Gram matrix inner dim, applied identically to A and B.
// posbuf (the subtracted positive) stays FP32-exact. Zeroes rowsum + queues.
__global__ __launch_bounds__(256) void k_prep(const float* __restrict__ z1,
                                              const float* __restrict__ z2,
                                              unsigned char* __restrict__ zn,
                                              float* __restrict__ posbuf,
                                              float* __restrict__ rowsum,
                                              int* __restrict__ qhead) {
  const int t = threadIdx.x;
  const int wv = t >> 6, lane = t & 63;
  const int r = blockIdx.x * 4 + wv;
  if (blockIdx.x < 32) rowsum[blockIdx.x * 256 + t] = 0.f;   // 32*256 = 8192
  if (blockIdx.x == 33 && t < 8) qhead[t] = 0;               // per-vxcd queues

  const float4* p1 = reinterpret_cast<const float4*>(z1 + (size_t)r * DIM) + (lane << 1);
  const float4* p2 = reinterpret_cast<const float4*>(z2 + (size_t)r * DIM) + (lane << 1);
  float4 a0 = p1[0], a1 = p1[1];
  float4 b0 = p2[0], b1 = p2[1];

  float s1 = a0.x * a0.x + a0.y * a0.y + a0.z * a0.z + a0.w * a0.w
           + a1.x * a1.x + a1.y * a1.y + a1.z * a1.z + a1.w * a1.w;
  float s2 = b0.x * b0.x + b0.y * b0.y + b0.z * b0.z + b0.w * b0.w
           + b1.x * b1.x + b1.y * b1.y + b1.z * b1.z + b1.w * b1.w;
  float sd = a0.x * b0.x + a0.y * b0.y + a0.z * b0.z + a0.w * b0.w
           + a1.x * b1.x + a1.y * b1.y + a1.z * b1.z + a1.w * b1.w;
#pragma unroll
  for (int off = 1; off < 64; off <<= 1) {
    s1 += __shfl_xor(s1, off, 64);
    s2 += __shfl_xor(s2, off, 64);
    sd += __shfl_xor(sd, off, 64);
  }
  const float sc1 = INV_SQRT_T / fmaxf(sqrtf(s1), 1e-8f);
  const float sc2 = INV_SQRT_T / fmaxf(sqrtf(s2), 1e-8f);

  float va[8] = {a0.x, a0.y, a0.z, a0.w, a1.x, a1.y, a1.z, a1.w};
  float vb[8] = {b0.x, b0.y, b0.z, b0.w, b1.x, b1.y, b1.z, b1.w};
  unsigned long long pa = 0, pb = 0;
#pragma unroll
  for (int d = 0; d < 8; d++) {
    __hip_fp8_e4m3 qa(va[d] * sc1);
    __hip_fp8_e4m3 qb(vb[d] * sc2);
    pa |= (unsigned long long)qa.__x << (8 * d);
    pb |= (unsigned long long)qb.__x << (8 * d);
  }
  // lane covers k = lane*8..+7 -> block = lane>>3, slot l = lane&7,
  // permuted position = block*64 + (l&3)*16 + (l>>2)*8
  const int pofs = (lane >> 3) * 64 + (lane & 3) * 16 + ((lane >> 2) & 1) * 8;
  *reinterpret_cast<unsigned long long*>(zn + (size_t)r * DIM + pofs) = pa;
  *reinterpret_cast<unsigned long long*>(zn + (size_t)(r + N_ROWS) * DIM + pofs) = pb;

  if (lane == 0) posbuf[r] = sd * sc1 * sc2;   // fp32-exact cos(z1_r,z2_r)/T
}

// ---------------------------------------------------------------------------
// Flash-LSE GEMM over upper-triangle 128x128 tiles -- FP8 e4m3, b128 reads.
// BODY per tile = r17 champion: 2 LDS buffers 32KB -> 4 blocks/CU, per iter
// {VMCNT(0); s_barrier; 8x ds_read_b128; STAGE(ks+1) under MFMA;
// setprio(1); 32x MFMA; setprio(0)}. K-permuted global layout + granule
// XOR swizzle (0 conflicts), super-tile (8x8) L2-locality tile order.
//
// THIS ROUND'S ONE CHANGE: PERSISTENT blocks + per-vxcd DYNAMIC tile
// queues. 1024 blocks (exactly 4/CU, one dispatch round); each block pulls
// tiles from queue[vxcd = blockIdx&7] (the same blockIdx%8~XCD correlation
// the static swizzle used), then steals from other queues when its own is
// dry (guarantees all 2080 tiles processed under any placement). Smooths
// the static schedule's quantization tail (32 CUs ran a 3rd ~19us round
// while 224 idled). Atomics are cheap (r12's cost was the threadfence --
// none here); queues are zeroed by k_prep in stream order every launch.
// LDS reuse across tiles is protected by the end-of-tile __syncthreads.
// ---------------------------------------------------------------------------
__global__ __launch_bounds__(256, 4) void k_lse(const unsigned char* __restrict__ Zn,
                                                float* __restrict__ rowsum,
                                                int* __restrict__ qhead) {
  __shared__ char smem[32768] __attribute__((aligned(16)));
  __shared__ int sh_g;
  const int tid  = threadIdx.x;
  const int wave = tid >> 6;
  const int lane = tid & 63;
  const int cl   = lane & 15;
  const int q    = lane >> 4;
  const int vx   = blockIdx.x & 7;

  const int wr = (wave >> 1) * 64;   // wave's row offset in tile
  const int wc = (wave & 1) * 64;    // wave's col offset in tile

  // staging geometry (tile-independent parts)
  const int r0  = tid >> 2;                              // 0..63
  const int sg  = ((tid & 3) ^ ((r0 >> 1) & 3)) * 16;    // pre-swizzled granule byte
  const int xk2 = (cl >> 1) & 3;        // read-side key (row bits from cl)
  const int gofs = ((q ^ xk2) << 4);    // granule byte offset within row

#define STAGE(d, it)                                                        \
  {                                                                         \
    char* _b = smem + (d) * 16384 + wave * 1024;                            \
    const int _ko = (it) * BKB;                                             \
    ASYNC_COPY16(gA0 + _ko,            _b);                                 \
    ASYNC_COPY16(gA0 + _ko + 64 * DIM, _b + 4096);                          \
    ASYNC_COPY16(gB0 + _ko,            _b + 8192);                          \
    ASYNC_COPY16(gB0 + _ko + 64 * DIM, _b + 12288);                         \
  }

  // pull tiles: own queue first, then steal round-robin.
  for (int qo = 0; qo < 8; ++qo) {
    const int qi = (vx + qo) & 7;
    for (;;) {
      if (tid == 0) sh_g = atomicAdd(&qhead[qi], 1);
      __syncthreads();
      const int gi = sh_g;
      if (gi >= QCAP) { __syncthreads(); break; }
      const int g = qi * QCAP + gi;

      // super-tile decode: 8x8 super-tiles (R<=C) row-major; sizes 36/64.
      int rem = g, R = 0, C = 0;
      for (;;) {
        const int sz = (C == R) ? 36 : 64;
        if (rem < sz) break;
        rem -= sz;
        C++;
        if (C == 8) { R++; C = R; }
      }
      int rt, ct;
      if (C == R) {
        int lr = 0;
        while (rem >= 8 - lr) { rem -= 8 - lr; lr++; }
        rt = R * 8 + lr;
        ct = C * 8 + lr + rem;
      } else {
        rt = R * 8 + (rem >> 3);
        ct = C * 8 + (rem & 7);
      }

      const unsigned char* gA0 = Zn + (size_t)(rt * 128 + r0) * DIM + sg;
      const unsigned char* gB0 = Zn + (size_t)(ct * 128 + r0) * DIM + sg;

      f32x4 acc[4][4] = {};

      STAGE(0, 0);
#pragma unroll
      for (int ks = 0; ks < NKS; ks++) {
        VMCNT(0);
        __builtin_amdgcn_s_barrier();
        asm volatile("" ::: "memory");

        const char* sA = smem + (ks & 1) * 16384;
        const char* sB = sA + 8192;
        fp8x8 af[2][4], bfr[2][4];
#pragma unroll
        for (int i = 0; i < 4; i++) {
          fp8x8x2 av = *reinterpret_cast<const fp8x8x2*>(sA + (wr + i * 16 + cl) * 64 + gofs);
          af[0][i] = av[0];
          af[1][i] = av[1];
        }
#pragma unroll
        for (int j = 0; j < 4; j++) {
          fp8x8x2 bv = *reinterpret_cast<const fp8x8x2*>(sB + (wc + j * 16 + cl) * 64 + gofs);
          bfr[0][j] = bv[0];
          bfr[1][j] = bv[1];
        }
        if (ks + 1 < NKS) STAGE((ks + 1) & 1, ks + 1);

        __builtin_amdgcn_s_setprio(1);
#pragma unroll
        for (int ksub = 0; ksub < 2; ksub++)
#pragma unroll
          for (int i = 0; i < 4; i++)
#pragma unroll
            for (int j = 0; j < 4; j++)
              acc[i][j] = __builtin_amdgcn_mfma_f32_16x16x32_fp8_fp8(af[ksub][i], bfr[ksub][j],
                                                                     acc[i][j], 0, 0, 0);
        __builtin_amdgcn_s_setprio(0);
      }

      // Epilogue: e = exp(s - C) with diagonal masked.
      // C-frag layout: col = cl, row = q*4 + r (dtype-independent on gfx950).
      const bool diagw = (rt == ct) && (wr == wc);
      float psum[4][4];
#pragma unroll
      for (int i = 0; i < 4; i++)
#pragma unroll
        for (int r = 0; r < 4; r++) psum[i][r] = 0.f;
      float colp[4] = {0.f, 0.f, 0.f, 0.f};

#pragma unroll
      for (int i = 0; i < 4; i++)
#pragma unroll
        for (int j = 0; j < 4; j++)
#pragma unroll
          for (int r = 0; r < 4; r++) {
            float e = exp2f(fmaf(acc[i][j][r], LOG2E, -C_LOG2E));
            if (diagw && (i == j) && (cl == q * 4 + r)) e = 0.f;
            psum[i][r] += e;
            colp[j] += e;
          }

#pragma unroll
      for (int i = 0; i < 4; i++)
#pragma unroll
        for (int r = 0; r < 4; r++) {
          float v = psum[i][r];
          v += __shfl_xor(v, 1, 64);
          v += __shfl_xor(v, 2, 64);
          v += __shfl_xor(v, 4, 64);
          v += __shfl_xor(v, 8, 64);
          if (cl == 0) atomicAdd(&rowsum[rt * 128 + wr + i * 16 + q * 4 + r], v);
        }

      if (rt != ct) {
#pragma unroll
        for (int j = 0; j < 4; j++) {
          float v = colp[j];
          v += __shfl_xor(v, 16, 64);
          v += __shfl_xor(v, 32, 64);
          if (q == 0) atomicAdd(&rowsum[ct * 128 + wc + j * 16 + cl], v);
        }
      }

      __syncthreads();   // LDS + sh_g safe for next tile
    }
  }
#undef STAGE
}

// Single-block finalize: 1024 threads, each handles 8 rows.
__global__ void k_final(const float* __restrict__ rowsum, const float* __restrict__ posbuf,
                        float* __restrict__ out) {
  __shared__ float red[16];
  const int t = threadIdx.x;   // 1024 threads
  float s = 0.f;
#pragma unroll
  for (int it = 0; it < TWO_N / 1024; it++) {
    const int row = it * 1024 + t;
    float v = logf(rowsum[row]);
    if (row < N_ROWS) v -= 2.f * posbuf[row];
    s += v;
  }
#pragma unroll
  for (int off = 32; off > 0; off >>= 1) s += __shfl_down(s, off, 64);
  if ((t & 63) == 0) red[t >> 6] = s;
  __syncthreads();
  if (t == 0) {
    float tot = 0.f;
#pragma unroll
    for (int i = 0; i < 16; i++) tot += red[i];
    out[0] = tot / (float)TWO_N + INV_T;
  }
}

extern "C" void kernel_launch(void* const* d_in, const int* in_sizes, int n_in,
                              void* d_out, int out_size, void* d_ws, size_t ws_size,
                              hipStream_t stream) {
  const float* z1 = (const float*)d_in[0];
  const float* z2 = (const float*)d_in[1];
  float* out = (float*)d_out;
  char* ws = (char*)d_ws;

  unsigned char* zn = (unsigned char*)ws;                 // 8192*512*1 = 4194304 B
  float* rowsum = (float*)(ws + 4194304);                 // 8192*4 = 32768 B
  float* posbuf = (float*)(ws + 4227072);                 // 4096*4 = 16384 B
  int* qhead    = (int*)(ws + 4243456);                   // 8*4 = 32 B

  k_prep<<<1024, 256, 0, stream>>>(z1, z2, zn, posbuf, rowsum, qhead);
  k_lse<<<1024, 256, 0, stream>>>(zn, rowsum, qhead);
  k_final<<<1, 1024, 0, stream>>>(rowsum, posbuf, out);
}

// Round 19
// 104.012 us; speedup vs baseline: 1.9885x; 1.9885x over previous
//
#include <hip/hip_runtime.h>
#include <hip/hip_bf16.h>
#include <hip/hip_fp8.h>

#define N_ROWS 4096
#define TWO_N 8192
#define DIM 512                             // elements per row; fp8 row = 512 B
#define BKB 64                              // K bytes per iter in fp8
#define NKS (DIM / BKB)                     // 8 K-steps
#define INV_T 14.285714285714286f           // 1/0.07
#define LOG2E 1.4426950408889634f
#define C_LOG2E 20.60992915555662f          // (1/0.07)*log2(e)
#define INV_SQRT_T 3.7796447300922722f      // 1/sqrt(0.07)

typedef float f32x4 __attribute__((ext_vector_type(4)));
typedef long fp8x8;                          // 8 fp8 = one 64-bit MFMA operand
typedef long fp8x8x2 __attribute__((ext_vector_type(2)));   // b128 = 2 operands

#define ASYNC_COPY16(gp, lp)                                                     \
  __builtin_amdgcn_global_load_lds((const __attribute__((address_space(1))) void*)(gp), \
                                   (__attribute__((address_space(3))) void*)(lp), 16, 0, 0)

#define VMCNT(n) asm volatile("s_waitcnt vmcnt(" #n ")" ::: "memory")

// Wave-per-row prep: float4 loads, butterfly shuffle reduce, fp8 e4m3 pack.
// Zn is stored K-PERMUTED: within each 64B k-block, 8B slot l (k=l*8..l*8+7)
// is placed at position (l&3)*16 + (l>>2)*8 (order [0,4,1,5,2,6,3,7]) so the
// two operands MFMA-lane q needs (slots q, q+4) are ADJACENT -> one b128
// read per fragment pair in k_lse. Exact: a global k-permutation of the
// Gram matrix inner dim, applied identically to A and B.
// posbuf (the subtracted positive) stays FP32-exact. Also zeroes rowsum.
__global__ __launch_bounds__(256) void k_prep(const float* __restrict__ z1,
                                              const float* __restrict__ z2,
                                              unsigned char* __restrict__ zn,
                                              float* __restrict__ posbuf,
                                              float* __restrict__ rowsum) {
  const int t = threadIdx.x;
  const int wv = t >> 6, lane = t & 63;
  const int r = blockIdx.x * 4 + wv;
  if (blockIdx.x < 32) rowsum[blockIdx.x * 256 + t] = 0.f;   // 32*256 = 8192

  const float4* p1 = reinterpret_cast<const float4*>(z1 + (size_t)r * DIM) + (lane << 1);
  const float4* p2 = reinterpret_cast<const float4*>(z2 + (size_t)r * DIM) + (lane << 1);
  float4 a0 = p1[0], a1 = p1[1];
  float4 b0 = p2[0], b1 = p2[1];

  float s1 = a0.x * a0.x + a0.y * a0.y + a0.z * a0.z + a0.w * a0.w
           + a1.x * a1.x + a1.y * a1.y + a1.z * a1.z + a1.w * a1.w;
  float s2 = b0.x * b0.x + b0.y * b0.y + b0.z * b0.z + b0.w * b0.w
           + b1.x * b1.x + b1.y * b1.y + b1.z * b1.z + b1.w * b1.w;
  float sd = a0.x * b0.x + a0.y * b0.y + a0.z * b0.z + a0.w * b0.w
           + a1.x * b1.x + a1.y * b1.y + a1.z * b1.z + a1.w * b1.w;
#pragma unroll
  for (int off = 1; off < 64; off <<= 1) {
    s1 += __shfl_xor(s1, off, 64);
    s2 += __shfl_xor(s2, off, 64);
    sd += __shfl_xor(sd, off, 64);
  }
  const float sc1 = INV_SQRT_T / fmaxf(sqrtf(s1), 1e-8f);
  const float sc2 = INV_SQRT_T / fmaxf(sqrtf(s2), 1e-8f);

  float va[8] = {a0.x, a0.y, a0.z, a0.w, a1.x, a1.y, a1.z, a1.w};
  float vb[8] = {b0.x, b0.y, b0.z, b0.w, b1.x, b1.y, b1.z, b1.w};
  unsigned long long pa = 0, pb = 0;
#pragma unroll
  for (int d = 0; d < 8; d++) {
    __hip_fp8_e4m3 qa(va[d] * sc1);
    __hip_fp8_e4m3 qb(vb[d] * sc2);
    pa |= (unsigned long long)qa.__x << (8 * d);
    pb |= (unsigned long long)qb.__x << (8 * d);
  }
  // lane covers k = lane*8..+7 -> block = lane>>3, slot l = lane&7,
  // permuted position = block*64 + (l&3)*16 + (l>>2)*8
  const int pofs = (lane >> 3) * 64 + (lane & 3) * 16 + ((lane >> 2) & 1) * 8;
  *reinterpret_cast<unsigned long long*>(zn + (size_t)r * DIM + pofs) = pa;
  *reinterpret_cast<unsigned long long*>(zn + (size_t)(r + N_ROWS) * DIM + pofs) = pb;

  if (lane == 0) posbuf[r] = sd * sc1 * sc2;   // fp32-exact cos(z1_r,z2_r)/T
}

// ---------------------------------------------------------------------------
// Flash-LSE GEMM over upper-triangle 128x128 tiles -- FP8 e4m3, b128 reads.
// CHAMPION (r17, 104.6us total): 2 LDS buffers 32KB -> 4 blocks/CU (the
// spill-free residency cap; 5 blk/CU spills VGPR 64->48, r16), per iter
// {VMCNT(0); s_barrier; 8x ds_read_b128; STAGE(ks+1) under MFMA;
// setprio(1); 32x MFMA; setprio(0)} (setprio +3.5% in the independent-
// co-resident-blocks regime, r17 = m191's positive case). K-permuted global
// layout + granule XOR swizzle (0 bank conflicts, r10), super-tile (8x8)
// L2-locality ordering (FETCH 12->6MB, r15), XCD-bijective block swizzle,
// STATIC tile assignment (r18's persistent+dynamic-queue variant regressed
// 3.6x: per-tile grab serialization + loss of cross-tile block overlap).
// ---------------------------------------------------------------------------
__global__ __launch_bounds__(256, 4) void k_lse(const unsigned char* __restrict__ Zn,
                                                float* __restrict__ rowsum) {
  __shared__ char smem[32768] __attribute__((aligned(16)));
  const int tid  = threadIdx.x;
  const int wave = tid >> 6;
  const int lane = tid & 63;
  const int cl   = lane & 15;
  const int q    = lane >> 4;

  // XCD-aware bijective swizzle: 2080 = 8 * 260.
  const int g = (blockIdx.x & 7) * 260 + (blockIdx.x >> 3);

  // super-tile decode: walk 8x8 super-tiles (R<=C) row-major; sizes 36/64.
  int rem = g, R = 0, C = 0;
  for (;;) {
    const int sz = (C == R) ? 36 : 64;
    if (rem < sz) break;
    rem -= sz;
    C++;
    if (C == 8) { R++; C = R; }
  }
  int rt, ct;
  if (C == R) {
    // triangular local index (row-major incl diagonal; row lr has 8-lr tiles)
    int lr = 0;
    while (rem >= 8 - lr) { rem -= 8 - lr; lr++; }
    rt = R * 8 + lr;
    ct = C * 8 + lr + rem;
  } else {
    rt = R * 8 + (rem >> 3);
    ct = C * 8 + (rem & 7);
  }

  const int wr = (wave >> 1) * 64;   // wave's row offset in tile
  const int wc = (wave & 1) * 64;    // wave's col offset in tile

  // staging: thread owns granules tid, tid+256 of each 128x64B tile
  const int r0  = tid >> 2;                              // 0..63
  const int sg  = ((tid & 3) ^ ((r0 >> 1) & 3)) * 16;    // pre-swizzled granule byte
  const unsigned char* gA0 = Zn + (size_t)(rt * 128 + r0) * DIM + sg;
  const unsigned char* gB0 = Zn + (size_t)(ct * 128 + r0) * DIM + sg;

  f32x4 acc[4][4] = {};
  const int xk2 = (cl >> 1) & 3;        // read-side key (row bits from cl)
  const int gofs = ((q ^ xk2) << 4);    // granule byte offset within row

#define STAGE(d, it)                                                        \
  {                                                                         \
    char* _b = smem + (d) * 16384 + wave * 1024;                            \
    const int _ko = (it) * BKB;                                             \
    ASYNC_COPY16(gA0 + _ko,            _b);                                 \
    ASYNC_COPY16(gA0 + _ko + 64 * DIM, _b + 4096);                          \
    ASYNC_COPY16(gB0 + _ko,            _b + 8192);                          \
    ASYNC_COPY16(gB0 + _ko + 64 * DIM, _b + 12288);                         \
  }

  STAGE(0, 0);
#pragma unroll
  for (int ks = 0; ks < NKS; ks++) {
    // own stage(ks) landed (issued ~a full iteration ago, mid-iter ks-1)
    VMCNT(0);
    __builtin_amdgcn_s_barrier();
    asm volatile("" ::: "memory");

    const char* sA = smem + (ks & 1) * 16384;
    const char* sB = sA + 8192;
    fp8x8 af[2][4], bfr[2][4];
#pragma unroll
    for (int i = 0; i < 4; i++) {
      fp8x8x2 av = *reinterpret_cast<const fp8x8x2*>(sA + (wr + i * 16 + cl) * 64 + gofs);
      af[0][i] = av[0];
      af[1][i] = av[1];
    }
#pragma unroll
    for (int j = 0; j < 4; j++) {
      fp8x8x2 bv = *reinterpret_cast<const fp8x8x2*>(sB + (wc + j * 16 + cl) * 64 + gofs);
      bfr[0][j] = bv[0];
      bfr[1][j] = bv[1];
    }
    // issue next stage under this iter's MFMA cluster; drained at next
    // iter's VMCNT(0). Target buffer was read at iter ks-1 (safe: barrier).
    if (ks + 1 < NKS) STAGE((ks + 1) & 1, ks + 1);

    __builtin_amdgcn_s_setprio(1);
#pragma unroll
    for (int ksub = 0; ksub < 2; ksub++)
#pragma unroll
      for (int i = 0; i < 4; i++)
#pragma unroll
        for (int j = 0; j < 4; j++)
          acc[i][j] = __builtin_amdgcn_mfma_f32_16x16x32_fp8_fp8(af[ksub][i], bfr[ksub][j],
                                                                 acc[i][j], 0, 0, 0);
    __builtin_amdgcn_s_setprio(0);
  }
#undef STAGE

  // Epilogue: e = exp(s - C) with diagonal masked.
  // C-frag layout: col = cl, row = q*4 + r (dtype-independent on gfx950).
  const bool diagw = (rt == ct) && (wr == wc);
  float psum[4][4];
#pragma unroll
  for (int i = 0; i < 4; i++)
#pragma unroll
    for (int r = 0; r < 4; r++) psum[i][r] = 0.f;
  float colp[4] = {0.f, 0.f, 0.f, 0.f};

#pragma unroll
  for (int i = 0; i < 4; i++)
#pragma unroll
    for (int j = 0; j < 4; j++)
#pragma unroll
      for (int r = 0; r < 4; r++) {
        float e = exp2f(fmaf(acc[i][j][r], LOG2E, -C_LOG2E));
        if (diagw && (i == j) && (cl == q * 4 + r)) e = 0.f;
        psum[i][r] += e;
        colp[j] += e;
      }

  // row sums -> rt rows (reduce across cols: cl lanes)
#pragma unroll
  for (int i = 0; i < 4; i++)
#pragma unroll
    for (int r = 0; r < 4; r++) {
      float v = psum[i][r];
      v += __shfl_xor(v, 1, 64);
      v += __shfl_xor(v, 2, 64);
      v += __shfl_xor(v, 4, 64);
      v += __shfl_xor(v, 8, 64);
      if (cl == 0) atomicAdd(&rowsum[rt * 128 + wr + i * 16 + q * 4 + r], v);
    }

  // col sums -> ct rows (reduce across rows: q lanes), off-diagonal tiles only
  if (rt != ct) {
#pragma unroll
    for (int j = 0; j < 4; j++) {
      float v = colp[j];
      v += __shfl_xor(v, 16, 64);
      v += __shfl_xor(v, 32, 64);
      if (q == 0) atomicAdd(&rowsum[ct * 128 + wc + j * 16 + cl], v);
    }
  }
}

// Single-block finalize: 1024 threads, each handles 8 rows.
__global__ void k_final(const float* __restrict__ rowsum, const float* __restrict__ posbuf,
                        float* __restrict__ out) {
  __shared__ float red[16];
  const int t = threadIdx.x;   // 1024 threads
  float s = 0.f;
#pragma unroll
  for (int it = 0; it < TWO_N / 1024; it++) {
    const int row = it * 1024 + t;
    float v = logf(rowsum[row]);
    if (row < N_ROWS) v -= 2.f * posbuf[row];
    s += v;
  }
#pragma unroll
  for (int off = 32; off > 0; off >>= 1) s += __shfl_down(s, off, 64);
  if ((t & 63) == 0) red[t >> 6] = s;
  __syncthreads();
  if (t == 0) {
    float tot = 0.f;
#pragma unroll
    for (int i = 0; i < 16; i++) tot += red[i];
    out[0] = tot / (float)TWO_N + INV_T;
  }
}

extern "C" void kernel_launch(void* const* d_in, const int* in_sizes, int n_in,
                              void* d_out, int out_size, void* d_ws, size_t ws_size,
                              hipStream_t stream) {
  const float* z1 = (const float*)d_in[0];
  const float* z2 = (const float*)d_in[1];
  float* out = (float*)d_out;
  char* ws = (char*)d_ws;

  unsigned char* zn = (unsigned char*)ws;                 // 8192*512*1 = 4194304 B
  float* rowsum = (float*)(ws + 4194304);                 // 8192*4 = 32768 B
  float* posbuf = (float*)(ws + 4227072);                 // 4096*4 = 16384 B

  k_prep<<<1024, 256, 0, stream>>>(z1, z2, zn, posbuf, rowsum);
  k_lse<<<2080, 256, 0, stream>>>(zn, rowsum);
  k_final<<<1, 1024, 0, stream>>>(rowsum, posbuf, out);
}